// Round 6
// baseline (303.674 us; speedup 1.0000x reference)
//
#include <hip/hip_runtime.h>
#include <stdint.h>

typedef __bf16 bf16_t;
typedef __bf16 bf16x8 __attribute__((ext_vector_type(8)));
typedef __bf16 bf16x4 __attribute__((ext_vector_type(4)));
typedef float  f32x4  __attribute__((ext_vector_type(4)));

#define DEV __device__ __forceinline__

constexpr int S = 2048, D = 1024, BATCH = 4, MF = BATCH * S;

// async global->LDS, 16B per lane. LDS dest is wave-uniform base + lane*16.
DEV void gload16(const void* g, void* l) {
  __builtin_amdgcn_global_load_lds(
      (const __attribute__((address_space(1))) void*)g,
      (__attribute__((address_space(3))) void*)(uint32_t)(uintptr_t)l,
      16, 0, 0);
}

// ---------------------------------------------------------------------------
// Shared NT GEMM body: C[m][n] = sum_k A[m][k]*B[n][k], bf16 in, fp32 acc.
// Tile 128x128, BK=64, 256 thr (4 waves, 2x2 of 64x64). 16-B chunks
// XOR-swizzled by (row&7) on the GLOBAL source side (keeps global_load_lds's
// lane-contiguous LDS dest) -> 0 bank conflicts on ds_read_b128 (verified R2).
// EP: 1 = QKV split: q/k bf16 [MF][D], vw transposed -> vwT[b][D][S], bias[n]
//     2 = scores: exp(acc/32) causal -> bf16 probs + partial row sums
//     3 = FINAL: out = acc * invl[row] + bo[n], fp32 (PV with folded Wo)
//     4 = plain bf16 out, ldc = D (WvoT precompute)
// ---------------------------------------------------------------------------
template<int EP>
DEV void gemm_body(int tm, int tn, int bz,
                   const bf16_t* __restrict__ A, const bf16_t* __restrict__ B,
                   void* __restrict__ C0, void* __restrict__ C1,
                   void* __restrict__ C2, const float* __restrict__ aux,
                   float* __restrict__ part, int K, int kmax,
                   bf16_t* ldsA, bf16_t* ldsB)
{
  const int m0 = tm * 128, n0 = tn * 128;
  const int tid  = threadIdx.x;
  const int lane = tid & 63;
  const int wave = tid >> 6;
  const int wm = wave & 1, wn = wave >> 1;
  const int l8r = lane >> 3;                  // row within 8-row staging block
  const int swz = ((lane & 7) ^ (lane >> 3)) * 8;  // swizzled k-chunk (elems)
  const int cl  = lane & 15;                  // fragment m/n index
  const int qd  = lane >> 4;                  // quad -> k-slice
  const int ch0 = ((qd ^ (cl & 7)) * 8);      // swizzled read chunk, kk=0

  f32x4 acc[4][4] = {};

  for (int k0 = 0; k0 < kmax; k0 += 64) {
    #pragma unroll
    for (int t = 0; t < 4; ++t) {
      const int rb = wave * 4 + t;
      gload16(A + (long)(m0 + rb * 8 + l8r) * K + (k0 + swz), &ldsA[rb * 512]);
      gload16(B + (long)(n0 + rb * 8 + l8r) * K + (k0 + swz), &ldsB[rb * 512]);
    }
    __syncthreads();
    #pragma unroll
    for (int kk = 0; kk < 64; kk += 32) {
      bf16x8 af[4], bg[4];
      #pragma unroll
      for (int i = 0; i < 4; ++i)
        af[i] = *(const bf16x8*)&ldsA[(wm * 64 + i * 16 + cl) * 64 + (ch0 ^ kk)];
      #pragma unroll
      for (int j = 0; j < 4; ++j)
        bg[j] = *(const bf16x8*)&ldsB[(wn * 64 + j * 16 + cl) * 64 + (ch0 ^ kk)];
      #pragma unroll
      for (int i = 0; i < 4; ++i)
        #pragma unroll
        for (int j = 0; j < 4; ++j)
          acc[i][j] = __builtin_amdgcn_mfma_f32_16x16x32_bf16(af[i], bg[j], acc[i][j], 0, 0, 0);
    }
    __syncthreads();
  }

  // Epilogues. C/D layout: col = lane&15, row = (lane>>4)*4 + reg.
  #pragma unroll
  for (int i = 0; i < 4; ++i) {
    const int gm0 = m0 + wm * 64 + i * 16 + qd * 4;

    if (EP == 1) {                            // fused QK+VW split store
      bf16_t* q  = (bf16_t*)C0;
      bf16_t* k  = (bf16_t*)C1;
      bf16_t* vwT = (bf16_t*)C2;
      #pragma unroll
      for (int j = 0; j < 4; ++j) {
        const int gn  = n0 + wn * 64 + j * 16 + cl;
        const int sec = gn >> 10, ln = gn & 1023;
        const float bn = aux[gn];
        if (sec == 2) {                       // vw: store transposed, 4x bf16
          const int z = gm0 >> 11, s0 = gm0 & 2047;
          bf16x4 v4;
          #pragma unroll
          for (int r = 0; r < 4; ++r) v4[r] = (bf16_t)(acc[i][j][r] + bn);
          *(bf16x4*)&vwT[((long)z * D + ln) * S + s0] = v4;
        } else {
          bf16_t* dst = (sec == 0) ? q : k;
          #pragma unroll
          for (int r = 0; r < 4; ++r)
            dst[(long)(gm0 + r) * D + ln] = (bf16_t)(acc[i][j][r] + bn);
        }
      }
    }

    if (EP == 2) {                            // scores -> exp probs + partials
      bf16_t* probs = (bf16_t*)C0 + (long)bz * S * S;
      float ls[4] = {0.f, 0.f, 0.f, 0.f};
      #pragma unroll
      for (int j = 0; j < 4; ++j) {
        const int gn = n0 + wn * 64 + j * 16 + cl;
        #pragma unroll
        for (int r = 0; r < 4; ++r) {
          const int gm = gm0 + r;
          const float e = (gn <= gm) ? __expf(acc[i][j][r] * 0.03125f) : 0.0f;
          probs[(long)gm * S + gn] = (bf16_t)e;
          ls[r] += e;
        }
      }
      #pragma unroll
      for (int r = 0; r < 4; ++r) {
        float v = ls[r];
        v += __shfl_xor(v, 1); v += __shfl_xor(v, 2);
        v += __shfl_xor(v, 4); v += __shfl_xor(v, 8);
        if (cl == 0)
          part[((long)bz * S + (gm0 + r)) * 32 + tn * 2 + wn] = v;
      }
    }

    if (EP == 3) {                            // FINAL: fp32 out, invl + bo
      float* out = (float*)C0 + (long)bz * S * D;
      const float* invl = aux + (long)bz * S;
      const float* bo = (const float*)C1;
      float scl[4];
      #pragma unroll
      for (int r = 0; r < 4; ++r) scl[r] = invl[gm0 + r];
      #pragma unroll
      for (int j = 0; j < 4; ++j) {
        const int gn = n0 + wn * 64 + j * 16 + cl;
        const float bn = bo[gn];
        #pragma unroll
        for (int r = 0; r < 4; ++r)
          out[(long)(gm0 + r) * D + gn] = acc[i][j][r] * scl[r] + bn;
      }
    }

    if (EP == 4) {                            // plain bf16 out (Wvo precomp)
      bf16_t* Co = (bf16_t*)C0;
      #pragma unroll
      for (int j = 0; j < 4; ++j) {
        const int gn = n0 + wn * 64 + j * 16 + cl;
        #pragma unroll
        for (int r = 0; r < 4; ++r)
          Co[(long)(gm0 + r) * D + gn] = (bf16_t)acc[i][j][r];
      }
    }
  }
}

// QK+VW projection: plain grid (64, 24) — R3's best config.
__global__ __launch_bounds__(256, 4) void gemm_qkv(
    const bf16_t* __restrict__ A, const bf16_t* __restrict__ B,
    bf16_t* q, bf16_t* k, bf16_t* vwT, const float* __restrict__ bias)
{
  __shared__ __align__(16) bf16_t lA[128 * 64], lB[128 * 64];
  gemm_body<1>(blockIdx.x, blockIdx.y, 0, A, B, q, k, vwT, bias, nullptr,
               1024, 1024, lA, lB);
}

// Scores: 544 blocks, blockIdx%8 = XCD: 2 XCDs/batch, each a contiguous
// 68-tile half of the triangle (L2 working-set chunking — R4 win).
__global__ __launch_bounds__(256, 4) void gemm_sc(
    const bf16_t* __restrict__ q, const bf16_t* __restrict__ k,
    bf16_t* probs, float* part)
{
  __shared__ __align__(16) bf16_t lA[128 * 64], lB[128 * 64];
  const int l = blockIdx.x, xcd = l & 7, idx = l >> 3;
  const int bz = xcd >> 1;
  const int t  = (xcd & 1) * 68 + idx;             // triangular index 0..135
  int tm = (int)((sqrtf(8.0f * t + 1.0f) - 1.0f) * 0.5f);
  while ((tm + 1) * (tm + 2) / 2 <= t) ++tm;
  while (tm * (tm + 1) / 2 > t) --tm;
  const int tn = t - tm * (tm + 1) / 2;
  gemm_body<2>(tm, tn, bz, q + (long)bz * S * D, k + (long)bz * S * D,
               probs, nullptr, nullptr, nullptr, part, 1024, 1024, lA, lB);
}

// Final PV(+folded Wo): 512 blocks, 2 XCDs/batch; m-pairs {m,15-m} -> each
// XCD gets exactly 68 k-tiles (balanced) with the 8 n-tiles of one m adjacent.
__global__ __launch_bounds__(256, 4) void gemm_pv_out(
    const bf16_t* __restrict__ probs, const bf16_t* __restrict__ vwT,
    float* out, const float* __restrict__ invl, const float* __restrict__ bo)
{
  __shared__ __align__(16) bf16_t lA[128 * 64], lB[128 * 64];
  const int l = blockIdx.x, xcd = l & 7, idx = l >> 3;
  const int bz = xcd >> 1, half = xcd & 1;
  const int slot = idx >> 3, tn = idx & 7;
  const int tm = (slot & 1) ? (slot - 1 + half) : (15 - half - slot);
  const int kmax = (tm + 1) * 128;
  gemm_body<3>(tm, tn, bz, probs + (long)bz * S * S, vwT + (long)bz * D * S,
               out, (void*)bo, nullptr, invl, nullptr, 2048, kmax, lA, lB);
}

// WvoT[c][i] = sum_n Wv[i][n] * Wo[n][c]  (so vw = x @ (Wv@Wo)).
// NT form: A[m=c][k=n] = WoT[c][n] = Wo[n][c]; B[n'=i][k=n] = Wv_nat[i][n].
// (R5 bug: fed WvT here -> summed over Wv's input index. Fixed: natural Wv.)
__global__ __launch_bounds__(256, 4) void gemm_wvo(
    const bf16_t* __restrict__ WoT, const bf16_t* __restrict__ WvN,
    bf16_t* WvoT)
{
  __shared__ __align__(16) bf16_t lA[128 * 64], lB[128 * 64];
  gemm_body<4>(blockIdx.x, blockIdx.y, 0, WoT, WvN, WvoT, nullptr, nullptr,
               nullptr, nullptr, 1024, 1024, lA, lB);
}

// inv_l[row] = 1 / sum(valid partials). Row tile tm has (tm+1)*2 valid entries.
__global__ __launch_bounds__(256) void reduce_invl(
    const float* __restrict__ part, float* __restrict__ invl)
{
  const int r = blockIdx.x * 256 + threadIdx.x;   // 0..MF-1
  const int row = r & (S - 1);
  const int cnt = ((row >> 7) + 1) * 2;
  const float* p = part + (long)r * 32;
  float s = 0.f;
  for (int j = 0; j < cnt; ++j) s += p[j];
  invl[r] = 1.0f / s;
}

// fp32 -> bf16 elementwise (x), 4 elems/thread
__global__ __launch_bounds__(256) void cvt_x(
    const float4* __restrict__ in, bf16x4* __restrict__ out, int n4)
{
  const int i = blockIdx.x * 256 + threadIdx.x;
  if (i >= n4) return;
  float4 f = in[i];
  bf16x4 o;
  o.x = (__bf16)f.x; o.y = (__bf16)f.y; o.z = (__bf16)f.z; o.w = (__bf16)f.w;
  out[i] = o;
}

// Weights -> bf16. z=0: Wq^T -> slot0; z=1: Wk^T -> slot1; z=3: Wo^T -> slot4
// (transposed via LDS). z=2: Wv plain cast (natural [i][n]) -> slot3.
// Slot 2 (WvoT) is filled by gemm_wvo.
__global__ __launch_bounds__(256) void cvt_w_t4(
    const float* __restrict__ W0, const float* __restrict__ W1,
    const float* __restrict__ W2, const float* __restrict__ W3,
    bf16_t* __restrict__ dst)
{
  const int zmap[4] = {0, 1, 3, 4};
  const float* W = (blockIdx.z == 0) ? W0 : (blockIdx.z == 1) ? W1
                 : (blockIdx.z == 2) ? W2 : W3;
  bf16_t* WT = dst + (size_t)zmap[blockIdx.z] * D * D;
  const int bx = blockIdx.x, by = blockIdx.y;
  const int tx = threadIdx.x & 31, ty = threadIdx.x >> 5;  // 32 x 8

  if (blockIdx.z == 2) {                      // Wv: plain cast, no transpose
    #pragma unroll
    for (int dy = 0; dy < 32; dy += 8) {
      const long idx = (long)(by * 32 + ty + dy) * 1024 + bx * 32 + tx;
      WT[idx] = (bf16_t)W[idx];
    }
    return;
  }

  __shared__ float t[32][33];
  #pragma unroll
  for (int dy = 0; dy < 32; dy += 8)
    t[ty + dy][tx] = W[(long)(by * 32 + ty + dy) * 1024 + bx * 32 + tx];
  __syncthreads();
  #pragma unroll
  for (int dy = 0; dy < 32; dy += 8)
    WT[(long)(bx * 32 + ty + dy) * 1024 + by * 32 + tx] = (bf16_t)t[tx][ty + dy];
}

// bias: [0:1024)=bq, [1024:2048)=bk, [2048:3072)=bvo where bvo[c]=sum bv[e]Wo[e][c]
__global__ __launch_bounds__(256) void stack_bias(
    const float* __restrict__ bq, const float* __restrict__ bk,
    const float* __restrict__ bv, const float* __restrict__ Wo,
    float* __restrict__ o)
{
  const int i = blockIdx.x * 256 + threadIdx.x;     // 0..3071
  if (i < 2048) {
    o[i] = (i < 1024) ? bq[i] : bk[i & 1023];
  } else {
    const int c = i - 2048;
    float s = 0.f;
    for (int e = 0; e < 1024; ++e) s += bv[e] * Wo[e * 1024 + c];
    o[i] = s;
  }
}

// ---------------------------------------------------------------------------
extern "C" void kernel_launch(void* const* d_in, const int* in_sizes, int n_in,
                              void* d_out, int out_size, void* d_ws, size_t ws_size,
                              hipStream_t stream) {
  const float* x  = (const float*)d_in[0];
  const float* Wq = (const float*)d_in[1];
  const float* bq = (const float*)d_in[2];
  const float* Wk = (const float*)d_in[3];
  const float* bk = (const float*)d_in[4];
  const float* Wv = (const float*)d_in[5];
  const float* bv = (const float*)d_in[6];
  const float* Wo = (const float*)d_in[7];
  const float* bo = (const float*)d_in[8];
  float* out = (float*)d_out;

  size_t off = 0;
  auto alloc = [&](size_t bytes) -> void* {
    void* p = (char*)d_ws + off;
    off += (bytes + 255) & ~(size_t)255;
    return p;
  };
  bf16_t* x_b   = (bf16_t*)alloc((size_t)MF * D * 2);          // 16.8 MB
  bf16_t* Wall  = (bf16_t*)alloc((size_t)5 * D * D * 2);       // [WqT|WkT|WvoT|WvN|WoT]
  float*  bqkv  = (float*) alloc((size_t)3 * D * 4);
  bf16_t* q_b   = (bf16_t*)alloc((size_t)MF * D * 2);
  bf16_t* k_b   = (bf16_t*)alloc((size_t)MF * D * 2);
  bf16_t* vwT_b = (bf16_t*)alloc((size_t)BATCH * D * S * 2);   // [b][D][S]
  bf16_t* probs = (bf16_t*)alloc((size_t)BATCH * S * S * 2);   // 33.5 MB
  float*  part  = (float*) alloc((size_t)MF * 32 * 4);         // 1 MB
  float*  invl  = (float*) alloc((size_t)MF * 4);
  bf16_t* WqkvT = Wall;                       // stacked B for QKV: [3D][D]
  bf16_t* WvoT  = Wall + (size_t)2 * D * D;
  bf16_t* WvN   = Wall + (size_t)3 * D * D;   // Wv natural layout, bf16
  bf16_t* WoT   = Wall + (size_t)4 * D * D;

  // 1. preamble: x -> bf16; weights -> bf16; bias stack (bvo = bv@Wo)
  cvt_x<<<dim3((MF * D / 4 + 255) / 256), 256, 0, stream>>>(
      (const float4*)x, (bf16x4*)x_b, MF * D / 4);
  cvt_w_t4<<<dim3(32, 32, 4), 256, 0, stream>>>(Wq, Wk, Wv, Wo, Wall);
  stack_bias<<<dim3(12), 256, 0, stream>>>(bq, bk, bv, Wo, bqkv);

  // 2. WvoT = (Wv@Wo)^T folded weight (so PV emits the final output directly)
  gemm_wvo<<<dim3(8, 8), 256, 0, stream>>>(WoT, WvN, WvoT);

  // 3. fused projection: [q|k|vw] = x @ [Wq|Wk|Wvo] + [bq|bk|bvo]
  gemm_qkv<<<dim3(64, 24), 256, 0, stream>>>(x_b, WqkvT, q_b, k_b, vwT_b, bqkv);

  // 4. scores = q k^T -> exp(./32) bf16 probs + partial row sums
  gemm_sc<<<dim3(544), 256, 0, stream>>>(q_b, k_b, probs, part);

  // 5. inv row sums
  reduce_invl<<<dim3(MF / 256), 256, 0, stream>>>(part, invl);

  // 6. out = (P vw) * invl + bo   (final, fp32, causal k-limit, XCD-balanced)
  gemm_pv_out<<<dim3(512), 256, 0, stream>>>(probs, vwT_b, out, invl, bo);
}

// Round 7
// 245.223 us; speedup vs baseline: 1.2384x; 1.2384x over previous
//
#include <hip/hip_runtime.h>
#include <stdint.h>

typedef __bf16 bf16_t;
typedef __bf16 bf16x8 __attribute__((ext_vector_type(8)));
typedef __bf16 bf16x4 __attribute__((ext_vector_type(4)));
typedef float  f32x4  __attribute__((ext_vector_type(4)));

#define DEV __device__ __forceinline__

constexpr int S = 2048, D = 1024, BATCH = 4, MF = BATCH * S;

// async global->LDS, 16B per lane. LDS dest is wave-uniform base + lane*16.
DEV void gload16(const void* g, void* l) {
  __builtin_amdgcn_global_load_lds(
      (const __attribute__((address_space(1))) void*)g,
      (__attribute__((address_space(3))) void*)(uint32_t)(uintptr_t)l,
      16, 0, 0);
}

// ---------------------------------------------------------------------------
// Shared NT GEMM body: C[m][n] = sum_k A[m][k]*B[n][k], bf16 in, fp32 acc.
// Tile 128x128, BK=64, 256 thr (4 waves, 2x2 of 64x64). 16-B chunks
// XOR-swizzled by (row&7) on the GLOBAL source side (keeps global_load_lds's
// lane-contiguous LDS dest) -> 0 bank conflicts on ds_read_b128 (verified R2).
// EP: 1 = QKV split: q/k bf16 [MF][D], vw transposed -> vwT[b][D][S], bias[n]
//     2 = scores: exp(acc/32) causal -> bf16 probs + partial row sums
//     3 = FINAL: out = acc * invl[row] + bo[n], fp32 (PV with folded Wo)
//     4 = plain bf16 out, ldc = D (WvoT precompute)
// ---------------------------------------------------------------------------
template<int EP>
DEV void gemm_body(int tm, int tn, int bz,
                   const bf16_t* __restrict__ A, const bf16_t* __restrict__ B,
                   void* __restrict__ C0, void* __restrict__ C1,
                   void* __restrict__ C2, const float* __restrict__ aux,
                   float* __restrict__ part, int K, int kmax,
                   bf16_t* ldsA, bf16_t* ldsB)
{
  const int m0 = tm * 128, n0 = tn * 128;
  const int tid  = threadIdx.x;
  const int lane = tid & 63;
  const int wave = tid >> 6;
  const int wm = wave & 1, wn = wave >> 1;
  const int l8r = lane >> 3;                  // row within 8-row staging block
  const int swz = ((lane & 7) ^ (lane >> 3)) * 8;  // swizzled k-chunk (elems)
  const int cl  = lane & 15;                  // fragment m/n index
  const int qd  = lane >> 4;                  // quad -> k-slice
  const int ch0 = ((qd ^ (cl & 7)) * 8);      // swizzled read chunk, kk=0

  f32x4 acc[4][4] = {};

  for (int k0 = 0; k0 < kmax; k0 += 64) {
    #pragma unroll
    for (int t = 0; t < 4; ++t) {
      const int rb = wave * 4 + t;
      gload16(A + (long)(m0 + rb * 8 + l8r) * K + (k0 + swz), &ldsA[rb * 512]);
      gload16(B + (long)(n0 + rb * 8 + l8r) * K + (k0 + swz), &ldsB[rb * 512]);
    }
    __syncthreads();
    #pragma unroll
    for (int kk = 0; kk < 64; kk += 32) {
      bf16x8 af[4], bg[4];
      #pragma unroll
      for (int i = 0; i < 4; ++i)
        af[i] = *(const bf16x8*)&ldsA[(wm * 64 + i * 16 + cl) * 64 + (ch0 ^ kk)];
      #pragma unroll
      for (int j = 0; j < 4; ++j)
        bg[j] = *(const bf16x8*)&ldsB[(wn * 64 + j * 16 + cl) * 64 + (ch0 ^ kk)];
      #pragma unroll
      for (int i = 0; i < 4; ++i)
        #pragma unroll
        for (int j = 0; j < 4; ++j)
          acc[i][j] = __builtin_amdgcn_mfma_f32_16x16x32_bf16(af[i], bg[j], acc[i][j], 0, 0, 0);
    }
    __syncthreads();
  }

  // Epilogues. C/D layout: col = lane&15, row = (lane>>4)*4 + reg.
  #pragma unroll
  for (int i = 0; i < 4; ++i) {
    const int gm0 = m0 + wm * 64 + i * 16 + qd * 4;

    if (EP == 1) {                            // fused QK+VW split store
      bf16_t* q  = (bf16_t*)C0;
      bf16_t* k  = (bf16_t*)C1;
      bf16_t* vwT = (bf16_t*)C2;
      #pragma unroll
      for (int j = 0; j < 4; ++j) {
        const int gn  = n0 + wn * 64 + j * 16 + cl;
        const int sec = gn >> 10, ln = gn & 1023;
        const float bn = aux[gn];
        if (sec == 2) {                       // vw: store transposed, 4x bf16
          const int z = gm0 >> 11, s0 = gm0 & 2047;
          bf16x4 v4;
          #pragma unroll
          for (int r = 0; r < 4; ++r) v4[r] = (bf16_t)(acc[i][j][r] + bn);
          *(bf16x4*)&vwT[((long)z * D + ln) * S + s0] = v4;
        } else {
          bf16_t* dst = (sec == 0) ? q : k;
          #pragma unroll
          for (int r = 0; r < 4; ++r)
            dst[(long)(gm0 + r) * D + ln] = (bf16_t)(acc[i][j][r] + bn);
        }
      }
    }

    if (EP == 2) {                            // scores -> exp probs + partials
      bf16_t* probs = (bf16_t*)C0 + (long)bz * S * S;
      float ls[4] = {0.f, 0.f, 0.f, 0.f};
      #pragma unroll
      for (int j = 0; j < 4; ++j) {
        const int gn = n0 + wn * 64 + j * 16 + cl;
        #pragma unroll
        for (int r = 0; r < 4; ++r) {
          const int gm = gm0 + r;
          const float e = (gn <= gm) ? __expf(acc[i][j][r] * 0.03125f) : 0.0f;
          probs[(long)gm * S + gn] = (bf16_t)e;
          ls[r] += e;
        }
      }
      #pragma unroll
      for (int r = 0; r < 4; ++r) {
        float v = ls[r];
        v += __shfl_xor(v, 1); v += __shfl_xor(v, 2);
        v += __shfl_xor(v, 4); v += __shfl_xor(v, 8);
        if (cl == 0)
          part[((long)bz * S + (gm0 + r)) * 32 + tn * 2 + wn] = v;
      }
    }

    if (EP == 3) {                            // FINAL: fp32 out, invl + bo
      float* out = (float*)C0 + (long)bz * S * D;
      const float* invl = aux + (long)bz * S;
      const float* bo = (const float*)C1;
      float scl[4];
      #pragma unroll
      for (int r = 0; r < 4; ++r) scl[r] = invl[gm0 + r];
      #pragma unroll
      for (int j = 0; j < 4; ++j) {
        const int gn = n0 + wn * 64 + j * 16 + cl;
        const float bn = bo[gn];
        #pragma unroll
        for (int r = 0; r < 4; ++r)
          out[(long)(gm0 + r) * D + gn] = acc[i][j][r] * scl[r] + bn;
      }
    }

    if (EP == 4) {                            // plain bf16 out (Wvo precomp)
      bf16_t* Co = (bf16_t*)C0;
      #pragma unroll
      for (int j = 0; j < 4; ++j) {
        const int gn = n0 + wn * 64 + j * 16 + cl;
        #pragma unroll
        for (int r = 0; r < 4; ++r)
          Co[(long)(gm0 + r) * D + gn] = (bf16_t)acc[i][j][r];
      }
    }
  }
}

// QK+VW projection: plain grid (64, 24) — R3's best config.
__global__ __launch_bounds__(256, 4) void gemm_qkv(
    const bf16_t* __restrict__ A, const bf16_t* __restrict__ B,
    bf16_t* q, bf16_t* k, bf16_t* vwT, const float* __restrict__ bias)
{
  __shared__ __align__(16) bf16_t lA[128 * 64], lB[128 * 64];
  gemm_body<1>(blockIdx.x, blockIdx.y, 0, A, B, q, k, vwT, bias, nullptr,
               1024, 1024, lA, lB);
}

// Scores: 544 blocks, blockIdx%8 = XCD: 2 XCDs/batch, each a contiguous
// 68-tile half of the triangle (L2 working-set chunking — R4 win).
__global__ __launch_bounds__(256, 4) void gemm_sc(
    const bf16_t* __restrict__ q, const bf16_t* __restrict__ k,
    bf16_t* probs, float* part)
{
  __shared__ __align__(16) bf16_t lA[128 * 64], lB[128 * 64];
  const int l = blockIdx.x, xcd = l & 7, idx = l >> 3;
  const int bz = xcd >> 1;
  const int t  = (xcd & 1) * 68 + idx;             // triangular index 0..135
  int tm = (int)((sqrtf(8.0f * t + 1.0f) - 1.0f) * 0.5f);
  while ((tm + 1) * (tm + 2) / 2 <= t) ++tm;
  while (tm * (tm + 1) / 2 > t) --tm;
  const int tn = t - tm * (tm + 1) / 2;
  gemm_body<2>(tm, tn, bz, q + (long)bz * S * D, k + (long)bz * S * D,
               probs, nullptr, nullptr, nullptr, part, 1024, 1024, lA, lB);
}

// Final PV(+folded Wo): 512 blocks, 2 XCDs/batch; m-pairs {m,15-m} -> each
// XCD gets exactly 68 k-tiles (balanced) with the 8 n-tiles of one m adjacent.
__global__ __launch_bounds__(256, 4) void gemm_pv_out(
    const bf16_t* __restrict__ probs, const bf16_t* __restrict__ vwT,
    float* out, const float* __restrict__ invl, const float* __restrict__ bo)
{
  __shared__ __align__(16) bf16_t lA[128 * 64], lB[128 * 64];
  const int l = blockIdx.x, xcd = l & 7, idx = l >> 3;
  const int bz = xcd >> 1, half = xcd & 1;
  const int slot = idx >> 3, tn = idx & 7;
  const int tm = (slot & 1) ? (slot - 1 + half) : (15 - half - slot);
  const int kmax = (tm + 1) * 128;
  gemm_body<3>(tm, tn, bz, probs + (long)bz * S * S, vwT + (long)bz * D * S,
               out, (void*)bo, nullptr, invl, nullptr, 2048, kmax, lA, lB);
}

// WvoT[c][i] = sum_n Wv[i][n] * Wo[n][c]  (so vw = x @ (Wv@Wo)).
// NT form: A[m=c][k=n] = WoT[c][n]; B[n'=i][k=n] = Wv natural [i][n].
__global__ __launch_bounds__(256, 4) void gemm_wvo(
    const bf16_t* __restrict__ WoT, const bf16_t* __restrict__ WvN,
    bf16_t* WvoT)
{
  __shared__ __align__(16) bf16_t lA[128 * 64], lB[128 * 64];
  gemm_body<4>(blockIdx.x, blockIdx.y, 0, WoT, WvN, WvoT, nullptr, nullptr,
               nullptr, nullptr, 1024, 1024, lA, lB);
}

// inv_l[row] = 1 / sum(valid partials). Row tile tm has (tm+1)*2 valid entries.
__global__ __launch_bounds__(256) void reduce_invl(
    const float* __restrict__ part, float* __restrict__ invl)
{
  const int r = blockIdx.x * 256 + threadIdx.x;   // 0..MF-1
  const int row = r & (S - 1);
  const int cnt = ((row >> 7) + 1) * 2;
  const float* p = part + (long)r * 32;
  float s = 0.f;
  for (int j = 0; j < cnt; ++j) s += p[j];
  invl[r] = 1.0f / s;
}

// fp32 -> bf16 elementwise (x), 4 elems/thread
__global__ __launch_bounds__(256) void cvt_x(
    const float4* __restrict__ in, bf16x4* __restrict__ out, int n4)
{
  const int i = blockIdx.x * 256 + threadIdx.x;
  if (i >= n4) return;
  float4 f = in[i];
  bf16x4 o;
  o.x = (__bf16)f.x; o.y = (__bf16)f.y; o.z = (__bf16)f.z; o.w = (__bf16)f.w;
  out[i] = o;
}

// Weights -> bf16. z=0: Wq^T -> slot0; z=1: Wk^T -> slot1; z=3: Wo^T -> slot4
// (transposed via LDS). z=2: Wv plain cast (natural [i][n]) -> slot3.
// Slot 2 (WvoT) is filled by gemm_wvo.
__global__ __launch_bounds__(256) void cvt_w_t4(
    const float* __restrict__ W0, const float* __restrict__ W1,
    const float* __restrict__ W2, const float* __restrict__ W3,
    bf16_t* __restrict__ dst)
{
  const int zmap[4] = {0, 1, 3, 4};
  const float* W = (blockIdx.z == 0) ? W0 : (blockIdx.z == 1) ? W1
                 : (blockIdx.z == 2) ? W2 : W3;
  bf16_t* WT = dst + (size_t)zmap[blockIdx.z] * D * D;
  const int bx = blockIdx.x, by = blockIdx.y;
  const int tx = threadIdx.x & 31, ty = threadIdx.x >> 5;  // 32 x 8

  if (blockIdx.z == 2) {                      // Wv: plain cast, no transpose
    #pragma unroll
    for (int dy = 0; dy < 32; dy += 8) {
      const long idx = (long)(by * 32 + ty + dy) * 1024 + bx * 32 + tx;
      WT[idx] = (bf16_t)W[idx];
    }
    return;
  }

  __shared__ float t[32][33];
  #pragma unroll
  for (int dy = 0; dy < 32; dy += 8)
    t[ty + dy][tx] = W[(long)(by * 32 + ty + dy) * 1024 + bx * 32 + tx];
  __syncthreads();
  #pragma unroll
  for (int dy = 0; dy < 32; dy += 8)
    WT[(long)(bx * 32 + ty + dy) * 1024 + by * 32 + tx] = (bf16_t)t[tx][ty + dy];
}

// bias build: blocks 0..255 -> bvo[c] = sum_e bv[e]*WoT[c][e], one wave per
// column c (coalesced 2KB row read + butterfly reduce). Blocks 256..259 copy
// bq/bk. (R6's version ran the bvo dot on 4 CUs with stride-4KB reads: ~75us
// serial bubble — this is the fix.)
__global__ __launch_bounds__(256) void bias_build(
    const float* __restrict__ bq, const float* __restrict__ bk,
    const float* __restrict__ bv, const bf16_t* __restrict__ WoT,
    float* __restrict__ o)
{
  const int b = blockIdx.x;
  if (b >= 256) {
    const int i = (b - 256) * 256 + threadIdx.x;   // 0..1023
    o[i] = bq[i];
    o[1024 + i] = bk[i];
    return;
  }
  const int wave = threadIdx.x >> 6, lane = threadIdx.x & 63;
  const int c = b * 4 + wave;
  const bf16_t* row = WoT + (long)c * 1024 + lane * 16;
  const float*  bvp = bv + lane * 16;
  float s = 0.f;
  #pragma unroll
  for (int j = 0; j < 16; ++j) s += bvp[j] * (float)row[j];
  #pragma unroll
  for (int sh = 32; sh > 0; sh >>= 1) s += __shfl_xor(s, sh, 64);
  if (lane == 0) o[2048 + c] = s;
}

// ---------------------------------------------------------------------------
extern "C" void kernel_launch(void* const* d_in, const int* in_sizes, int n_in,
                              void* d_out, int out_size, void* d_ws, size_t ws_size,
                              hipStream_t stream) {
  const float* x  = (const float*)d_in[0];
  const float* Wq = (const float*)d_in[1];
  const float* bq = (const float*)d_in[2];
  const float* Wk = (const float*)d_in[3];
  const float* bk = (const float*)d_in[4];
  const float* Wv = (const float*)d_in[5];
  const float* bv = (const float*)d_in[6];
  const float* Wo = (const float*)d_in[7];
  const float* bo = (const float*)d_in[8];
  float* out = (float*)d_out;

  size_t off = 0;
  auto alloc = [&](size_t bytes) -> void* {
    void* p = (char*)d_ws + off;
    off += (bytes + 255) & ~(size_t)255;
    return p;
  };
  bf16_t* x_b   = (bf16_t*)alloc((size_t)MF * D * 2);          // 16.8 MB
  bf16_t* Wall  = (bf16_t*)alloc((size_t)5 * D * D * 2);       // [WqT|WkT|WvoT|WvN|WoT]
  float*  bqkv  = (float*) alloc((size_t)3 * D * 4);
  bf16_t* q_b   = (bf16_t*)alloc((size_t)MF * D * 2);
  bf16_t* k_b   = (bf16_t*)alloc((size_t)MF * D * 2);
  bf16_t* vwT_b = (bf16_t*)alloc((size_t)BATCH * D * S * 2);   // [b][D][S]
  bf16_t* probs = (bf16_t*)alloc((size_t)BATCH * S * S * 2);   // 33.5 MB
  float*  part  = (float*) alloc((size_t)MF * 32 * 4);         // 1 MB
  float*  invl  = (float*) alloc((size_t)MF * 4);
  bf16_t* WqkvT = Wall;                       // stacked B for QKV: [3D][D]
  bf16_t* WvoT  = Wall + (size_t)2 * D * D;
  bf16_t* WvN   = Wall + (size_t)3 * D * D;   // Wv natural layout, bf16
  bf16_t* WoT   = Wall + (size_t)4 * D * D;

  // 1. preamble: x -> bf16; weights -> bf16; bias (bvo via WoT, parallel)
  cvt_x<<<dim3((MF * D / 4 + 255) / 256), 256, 0, stream>>>(
      (const float4*)x, (bf16x4*)x_b, MF * D / 4);
  cvt_w_t4<<<dim3(32, 32, 4), 256, 0, stream>>>(Wq, Wk, Wv, Wo, Wall);
  bias_build<<<dim3(260), 256, 0, stream>>>(bq, bk, bv, WoT, bqkv);

  // 2. WvoT = (Wv@Wo)^T folded weight (so PV emits the final output directly)
  gemm_wvo<<<dim3(8, 8), 256, 0, stream>>>(WoT, WvN, WvoT);

  // 3. fused projection: [q|k|vw] = x @ [Wq|Wk|Wvo] + [bq|bk|bvo]
  gemm_qkv<<<dim3(64, 24), 256, 0, stream>>>(x_b, WqkvT, q_b, k_b, vwT_b, bqkv);

  // 4. scores = q k^T -> exp(./32) bf16 probs + partial row sums
  gemm_sc<<<dim3(544), 256, 0, stream>>>(q_b, k_b, probs, part);

  // 5. inv row sums
  reduce_invl<<<dim3(MF / 256), 256, 0, stream>>>(part, invl);

  // 6. out = (P vw) * invl + bo   (final, fp32, causal k-limit, XCD-balanced)
  gemm_pv_out<<<dim3(512), 256, 0, stream>>>(probs, vwT_b, out, invl, bo);
}

// Round 8
// 244.788 us; speedup vs baseline: 1.2406x; 1.0018x over previous
//
#include <hip/hip_runtime.h>
#include <stdint.h>

typedef __bf16 bf16_t;
typedef __bf16 bf16x8 __attribute__((ext_vector_type(8)));
typedef __bf16 bf16x4 __attribute__((ext_vector_type(4)));
typedef float  f32x4  __attribute__((ext_vector_type(4)));

#define DEV __device__ __forceinline__

constexpr int S = 2048, D = 1024, BATCH = 4, MF = BATCH * S;

// async global->LDS, 16B per lane. LDS dest is wave-uniform base + lane*16.
DEV void gload16(const void* g, void* l) {
  __builtin_amdgcn_global_load_lds(
      (const __attribute__((address_space(1))) void*)g,
      (__attribute__((address_space(3))) void*)(uint32_t)(uintptr_t)l,
      16, 0, 0);
}

// ---------------------------------------------------------------------------
// bf16 NT GEMM body (as R7): C[m][n] = sum_k A[m][k]*B[n][k], fp32 acc.
// Tile 128x128, BK=64, 256 thr (4 waves, 2x2 of 64x64). 16-B chunks
// XOR-swizzled by (row&7) on the GLOBAL source side -> 0 bank conflicts.
// EP: 1 = QKV split: q/k -> fp8 [MF][D], vw transposed bf16 -> vwT[b][D][S]
//     3 = FINAL: out = acc * invl[row] + bo[n], fp32 (PV with folded Wo)
//     4 = plain bf16 out, ldc = D (WvoT precompute)
// ---------------------------------------------------------------------------
template<int EP>
DEV void gemm_body(int tm, int tn, int bz,
                   const bf16_t* __restrict__ A, const bf16_t* __restrict__ B,
                   void* __restrict__ C0, void* __restrict__ C1,
                   void* __restrict__ C2, const float* __restrict__ aux,
                   int K, int kmax, bf16_t* ldsA, bf16_t* ldsB)
{
  const int m0 = tm * 128, n0 = tn * 128;
  const int tid  = threadIdx.x;
  const int lane = tid & 63;
  const int wave = tid >> 6;
  const int wm = wave & 1, wn = wave >> 1;
  const int l8r = lane >> 3;                  // row within 8-row staging block
  const int swz = ((lane & 7) ^ (lane >> 3)) * 8;  // swizzled k-chunk (elems)
  const int cl  = lane & 15;                  // fragment m/n index
  const int qd  = lane >> 4;                  // quad -> k-slice
  const int ch0 = ((qd ^ (cl & 7)) * 8);      // swizzled read chunk, kk=0

  f32x4 acc[4][4] = {};

  for (int k0 = 0; k0 < kmax; k0 += 64) {
    #pragma unroll
    for (int t = 0; t < 4; ++t) {
      const int rb = wave * 4 + t;
      gload16(A + (long)(m0 + rb * 8 + l8r) * K + (k0 + swz), &ldsA[rb * 512]);
      gload16(B + (long)(n0 + rb * 8 + l8r) * K + (k0 + swz), &ldsB[rb * 512]);
    }
    __syncthreads();
    #pragma unroll
    for (int kk = 0; kk < 64; kk += 32) {
      bf16x8 af[4], bg[4];
      #pragma unroll
      for (int i = 0; i < 4; ++i)
        af[i] = *(const bf16x8*)&ldsA[(wm * 64 + i * 16 + cl) * 64 + (ch0 ^ kk)];
      #pragma unroll
      for (int j = 0; j < 4; ++j)
        bg[j] = *(const bf16x8*)&ldsB[(wn * 64 + j * 16 + cl) * 64 + (ch0 ^ kk)];
      #pragma unroll
      for (int i = 0; i < 4; ++i)
        #pragma unroll
        for (int j = 0; j < 4; ++j)
          acc[i][j] = __builtin_amdgcn_mfma_f32_16x16x32_bf16(af[i], bg[j], acc[i][j], 0, 0, 0);
    }
    __syncthreads();
  }

  // Epilogues. C/D layout: col = lane&15, row = (lane>>4)*4 + reg.
  #pragma unroll
  for (int i = 0; i < 4; ++i) {
    const int gm0 = m0 + wm * 64 + i * 16 + qd * 4;

    if (EP == 1) {                            // QK (fp8) + VW (bf16) split
      uint8_t* q8 = (uint8_t*)C0;
      uint8_t* k8 = (uint8_t*)C1;
      bf16_t* vwT = (bf16_t*)C2;
      #pragma unroll
      for (int j = 0; j < 4; ++j) {
        const int gn  = n0 + wn * 64 + j * 16 + cl;
        const int sec = gn >> 10, ln = gn & 1023;
        const float bn = aux[gn];
        if (sec == 2) {                       // vw: store transposed, 4x bf16
          const int z = gm0 >> 11, s0 = gm0 & 2047;
          bf16x4 v4;
          #pragma unroll
          for (int r = 0; r < 4; ++r) v4[r] = (bf16_t)(acc[i][j][r] + bn);
          *(bf16x4*)&vwT[((long)z * D + ln) * S + s0] = v4;
        } else {
          uint8_t* dst = (sec == 0) ? q8 : k8;
          #pragma unroll
          for (int r = 0; r < 4; ++r) {
            const float v = acc[i][j][r] + bn;
            const int p = __builtin_amdgcn_cvt_pk_fp8_f32(v, v, 0, false);
            dst[(long)(gm0 + r) * D + ln] = (uint8_t)(p & 0xFF);
          }
        }
      }
    }

    if (EP == 3) {                            // FINAL: fp32 out, invl + bo
      float* out = (float*)C0 + (long)bz * S * D;
      const float* invl = aux + (long)bz * S;
      const float* bo = (const float*)C1;
      float scl[4];
      #pragma unroll
      for (int r = 0; r < 4; ++r) scl[r] = invl[gm0 + r];
      #pragma unroll
      for (int j = 0; j < 4; ++j) {
        const int gn = n0 + wn * 64 + j * 16 + cl;
        const float bn = bo[gn];
        #pragma unroll
        for (int r = 0; r < 4; ++r)
          out[(long)(gm0 + r) * D + gn] = acc[i][j][r] * scl[r] + bn;
      }
    }

    if (EP == 4) {                            // plain bf16 out (Wvo precomp)
      bf16_t* Co = (bf16_t*)C0;
      #pragma unroll
      for (int j = 0; j < 4; ++j) {
        const int gn = n0 + wn * 64 + j * 16 + cl;
        #pragma unroll
        for (int r = 0; r < 4; ++r)
          Co[(long)(gm0 + r) * D + gn] = (bf16_t)acc[i][j][r];
      }
    }
  }
}

// QK+VW projection: plain grid (64, 24).
__global__ __launch_bounds__(256, 4) void gemm_qkv(
    const bf16_t* __restrict__ A, const bf16_t* __restrict__ B,
    uint8_t* q8, uint8_t* k8, bf16_t* vwT, const float* __restrict__ bias)
{
  __shared__ __align__(16) bf16_t lA[128 * 64], lB[128 * 64];
  gemm_body<1>(blockIdx.x, blockIdx.y, 0, A, B, q8, k8, vwT, bias,
               1024, 1024, lA, lB);
}

// ---------------------------------------------------------------------------
// fp8 scores kernel: probs = exp(q8·k8^T / 32) causal, bf16 + partial sums.
// Same 128x128 tile geometry; LDS rows = 64 fp8 = 64 B. 16-B granules
// XOR-swizzled by (row>>1)&3 (global-source side) -> <=2-way conflicts (free).
// mfma_f32_16x16x32_fp8_fp8: A/B operand = 8 bytes (long), k = quad*8+[0..7].
// 544 blocks, blockIdx%8 = XCD, 2 XCDs/batch, 68-tile triangle halves (R4).
// ---------------------------------------------------------------------------
__global__ __launch_bounds__(256, 4) void gemm_sc8(
    const uint8_t* __restrict__ q8g, const uint8_t* __restrict__ k8g,
    bf16_t* __restrict__ probs_g, float* __restrict__ part)
{
  __shared__ __align__(16) uint8_t lA[128 * 64], lB[128 * 64];
  const int l = blockIdx.x, xcd = l & 7, idx = l >> 3;
  const int bz = xcd >> 1;
  const int t  = (xcd & 1) * 68 + idx;             // triangular index 0..135
  int tm = (int)((sqrtf(8.0f * t + 1.0f) - 1.0f) * 0.5f);
  while ((tm + 1) * (tm + 2) / 2 <= t) ++tm;
  while (tm * (tm + 1) / 2 > t) --tm;
  const int tn = t - tm * (tm + 1) / 2;
  const int m0 = tm * 128, n0 = tn * 128;
  const uint8_t* q8 = q8g + (long)bz * S * D;
  const uint8_t* k8 = k8g + (long)bz * S * D;

  const int tid  = threadIdx.x;
  const int lane = tid & 63;
  const int wave = tid >> 6;
  const int wm = wave & 1, wn = wave >> 1;
  const int srow = lane >> 2;                      // staging row in 16-slab
  const int sgr  = (lane & 3) ^ ((lane >> 3) & 3); // swizzled source granule
  const int cl = lane & 15, qd = lane >> 4;
  const int sfr = (cl >> 1) & 3;                   // frag-read swizzle key
  const int half8 = (qd & 1) * 8;

  f32x4 acc[4][4] = {};

  for (int k0 = 0; k0 < 1024; k0 += 64) {
    #pragma unroll
    for (int tt = 0; tt < 2; ++tt) {
      const int rb = wave * 2 + tt;                // 16-row slab (0..7)
      const int gr = rb * 16 + srow;
      gload16(q8 + (long)(m0 + gr) * 1024 + k0 + sgr * 16, &lA[rb * 1024]);
      gload16(k8 + (long)(n0 + gr) * 1024 + k0 + sgr * 16, &lB[rb * 1024]);
    }
    __syncthreads();
    #pragma unroll
    for (int kk = 0; kk < 2; ++kk) {
      long a[4], b[4];
      const int pg = ((kk << 1) + (qd >> 1)) ^ sfr;
      #pragma unroll
      for (int i = 0; i < 4; ++i)
        a[i] = *(const long*)&lA[(wm * 64 + i * 16 + cl) * 64 + pg * 16 + half8];
      #pragma unroll
      for (int j = 0; j < 4; ++j)
        b[j] = *(const long*)&lB[(wn * 64 + j * 16 + cl) * 64 + pg * 16 + half8];
      #pragma unroll
      for (int i = 0; i < 4; ++i)
        #pragma unroll
        for (int j = 0; j < 4; ++j)
          acc[i][j] = __builtin_amdgcn_mfma_f32_16x16x32_fp8_fp8(a[i], b[j], acc[i][j], 0, 0, 0);
    }
    __syncthreads();
  }

  // epilogue: exp(acc/32) causal -> bf16 probs + partial row sums
  bf16_t* probs = probs_g + (long)bz * S * S;
  #pragma unroll
  for (int i = 0; i < 4; ++i) {
    const int gm0 = m0 + wm * 64 + i * 16 + qd * 4;
    float ls[4] = {0.f, 0.f, 0.f, 0.f};
    #pragma unroll
    for (int j = 0; j < 4; ++j) {
      const int gn = n0 + wn * 64 + j * 16 + cl;
      #pragma unroll
      for (int r = 0; r < 4; ++r) {
        const int gm = gm0 + r;
        const float e = (gn <= gm) ? __expf(acc[i][j][r] * 0.03125f) : 0.0f;
        probs[(long)gm * S + gn] = (bf16_t)e;
        ls[r] += e;
      }
    }
    #pragma unroll
    for (int r = 0; r < 4; ++r) {
      float v = ls[r];
      v += __shfl_xor(v, 1); v += __shfl_xor(v, 2);
      v += __shfl_xor(v, 4); v += __shfl_xor(v, 8);
      if (cl == 0)
        part[((long)bz * S + (gm0 + r)) * 32 + tn * 2 + wn] = v;
    }
  }
}

// Final PV(+folded Wo): 512 blocks, 2 XCDs/batch. Per-CU exact K balance:
// within an XCD (64 blocks on 32 CUs, idx c pairs with c+32), idx<32 take
// long-K m's {15,13,11,9}-half, idx>=32 take {0,2,4,6}+half with matching g
// -> every CU gets exactly 17 k-tiles. (R7 paired slots (s,s+4): 6..28.)
__global__ __launch_bounds__(256, 4) void gemm_pv_out(
    const bf16_t* __restrict__ probs, const bf16_t* __restrict__ vwT,
    float* out, const float* __restrict__ invl, const float* __restrict__ bo)
{
  __shared__ __align__(16) bf16_t lA[128 * 64], lB[128 * 64];
  const int l = blockIdx.x, xcd = l & 7, idx = l >> 3;
  const int bz = xcd >> 1, half = xcd & 1;
  const int g = (idx >> 3) & 3, tn = idx & 7;
  const int tm = (idx < 32) ? (15 - half - 2 * g) : (2 * g + half);
  const int kmax = (tm + 1) * 128;
  gemm_body<3>(tm, tn, bz, probs + (long)bz * S * S, vwT + (long)bz * D * S,
               out, (void*)bo, nullptr, invl, 2048, kmax, lA, lB);
}

// WvoT[c][i] = sum_n Wv[i][n] * Wo[n][c]  (so vw = x @ (Wv@Wo)).
__global__ __launch_bounds__(256, 4) void gemm_wvo(
    const bf16_t* __restrict__ WoT, const bf16_t* __restrict__ WvN,
    bf16_t* WvoT)
{
  __shared__ __align__(16) bf16_t lA[128 * 64], lB[128 * 64];
  gemm_body<4>(blockIdx.x, blockIdx.y, 0, WoT, WvN, WvoT, nullptr, nullptr,
               nullptr, 1024, 1024, lA, lB);
}

// inv_l[row] = 1 / sum(valid partials). Row tile tm has (tm+1)*2 valid entries.
__global__ __launch_bounds__(256) void reduce_invl(
    const float* __restrict__ part, float* __restrict__ invl)
{
  const int r = blockIdx.x * 256 + threadIdx.x;   // 0..MF-1
  const int row = r & (S - 1);
  const int cnt = ((row >> 7) + 1) * 2;
  const float* p = part + (long)r * 32;
  float s = 0.f;
  for (int j = 0; j < cnt; ++j) s += p[j];
  invl[r] = 1.0f / s;
}

// fp32 -> bf16 elementwise (x), 4 elems/thread
__global__ __launch_bounds__(256) void cvt_x(
    const float4* __restrict__ in, bf16x4* __restrict__ out, int n4)
{
  const int i = blockIdx.x * 256 + threadIdx.x;
  if (i >= n4) return;
  float4 f = in[i];
  bf16x4 o;
  o.x = (__bf16)f.x; o.y = (__bf16)f.y; o.z = (__bf16)f.z; o.w = (__bf16)f.w;
  out[i] = o;
}

// Weights -> bf16. z=0: Wq^T -> slot0; z=1: Wk^T -> slot1; z=3: Wo^T -> slot4
// (transposed via LDS). z=2: Wv plain cast (natural [i][n]) -> slot3.
// Slot 2 (WvoT) is filled by gemm_wvo.
__global__ __launch_bounds__(256) void cvt_w_t4(
    const float* __restrict__ W0, const float* __restrict__ W1,
    const float* __restrict__ W2, const float* __restrict__ W3,
    bf16_t* __restrict__ dst)
{
  const int zmap[4] = {0, 1, 3, 4};
  const float* W = (blockIdx.z == 0) ? W0 : (blockIdx.z == 1) ? W1
                 : (blockIdx.z == 2) ? W2 : W3;
  bf16_t* WT = dst + (size_t)zmap[blockIdx.z] * D * D;
  const int bx = blockIdx.x, by = blockIdx.y;
  const int tx = threadIdx.x & 31, ty = threadIdx.x >> 5;  // 32 x 8

  if (blockIdx.z == 2) {                      // Wv: plain cast, no transpose
    #pragma unroll
    for (int dy = 0; dy < 32; dy += 8) {
      const long idx = (long)(by * 32 + ty + dy) * 1024 + bx * 32 + tx;
      WT[idx] = (bf16_t)W[idx];
    }
    return;
  }

  __shared__ float t[32][33];
  #pragma unroll
  for (int dy = 0; dy < 32; dy += 8)
    t[ty + dy][tx] = W[(long)(by * 32 + ty + dy) * 1024 + bx * 32 + tx];
  __syncthreads();
  #pragma unroll
  for (int dy = 0; dy < 32; dy += 8)
    WT[(long)(bx * 32 + ty + dy) * 1024 + by * 32 + tx] = (bf16_t)t[tx][ty + dy];
}

// bias build: blocks 0..255 -> bvo[c] = sum_e bv[e]*WoT[c][e], one wave per
// column (coalesced row read + butterfly). Blocks 256..259 copy bq/bk.
__global__ __launch_bounds__(256) void bias_build(
    const float* __restrict__ bq, const float* __restrict__ bk,
    const float* __restrict__ bv, const bf16_t* __restrict__ WoT,
    float* __restrict__ o)
{
  const int b = blockIdx.x;
  if (b >= 256) {
    const int i = (b - 256) * 256 + threadIdx.x;   // 0..1023
    o[i] = bq[i];
    o[1024 + i] = bk[i];
    return;
  }
  const int wave = threadIdx.x >> 6, lane = threadIdx.x & 63;
  const int c = b * 4 + wave;
  const bf16_t* row = WoT + (long)c * 1024 + lane * 16;
  const float*  bvp = bv + lane * 16;
  float s = 0.f;
  #pragma unroll
  for (int j = 0; j < 16; ++j) s += bvp[j] * (float)row[j];
  #pragma unroll
  for (int sh = 32; sh > 0; sh >>= 1) s += __shfl_xor(s, sh, 64);
  if (lane == 0) o[2048 + c] = s;
}

// ---------------------------------------------------------------------------
extern "C" void kernel_launch(void* const* d_in, const int* in_sizes, int n_in,
                              void* d_out, int out_size, void* d_ws, size_t ws_size,
                              hipStream_t stream) {
  const float* x  = (const float*)d_in[0];
  const float* Wq = (const float*)d_in[1];
  const float* bq = (const float*)d_in[2];
  const float* Wk = (const float*)d_in[3];
  const float* bk = (const float*)d_in[4];
  const float* Wv = (const float*)d_in[5];
  const float* bv = (const float*)d_in[6];
  const float* Wo = (const float*)d_in[7];
  const float* bo = (const float*)d_in[8];
  float* out = (float*)d_out;

  size_t off = 0;
  auto alloc = [&](size_t bytes) -> void* {
    void* p = (char*)d_ws + off;
    off += (bytes + 255) & ~(size_t)255;
    return p;
  };
  bf16_t* x_b   = (bf16_t*)alloc((size_t)MF * D * 2);          // 16.8 MB
  bf16_t* Wall  = (bf16_t*)alloc((size_t)5 * D * D * 2);       // [WqT|WkT|WvoT|WvN|WoT]
  float*  bqkv  = (float*) alloc((size_t)3 * D * 4);
  uint8_t* q8   = (uint8_t*)alloc((size_t)MF * D);             // 8.4 MB fp8
  uint8_t* k8   = (uint8_t*)alloc((size_t)MF * D);             // 8.4 MB fp8
  bf16_t* vwT_b = (bf16_t*)alloc((size_t)BATCH * D * S * 2);   // [b][D][S]
  bf16_t* probs = (bf16_t*)alloc((size_t)BATCH * S * S * 2);   // 33.5 MB
  float*  part  = (float*) alloc((size_t)MF * 32 * 4);         // 1 MB
  float*  invl  = (float*) alloc((size_t)MF * 4);
  bf16_t* WqkvT = Wall;                       // stacked B for QKV: [3D][D]
  bf16_t* WvoT  = Wall + (size_t)2 * D * D;
  bf16_t* WvN   = Wall + (size_t)3 * D * D;   // Wv natural layout, bf16
  bf16_t* WoT   = Wall + (size_t)4 * D * D;

  // 1. preamble: x -> bf16; weights -> bf16; bias (bvo via WoT, parallel)
  cvt_x<<<dim3((MF * D / 4 + 255) / 256), 256, 0, stream>>>(
      (const float4*)x, (bf16x4*)x_b, MF * D / 4);
  cvt_w_t4<<<dim3(32, 32, 4), 256, 0, stream>>>(Wq, Wk, Wv, Wo, Wall);
  bias_build<<<dim3(260), 256, 0, stream>>>(bq, bk, bv, WoT, bqkv);

  // 2. WvoT = (Wv@Wo)^T folded weight (so PV emits the final output directly)
  gemm_wvo<<<dim3(8, 8), 256, 0, stream>>>(WoT, WvN, WvoT);

  // 3. fused projection: q/k in fp8 e4m3, vw bf16 transposed
  gemm_qkv<<<dim3(64, 24), 256, 0, stream>>>(x_b, WqkvT, q8, k8, vwT_b, bqkv);

  // 4. scores (fp8 MFMA) -> exp(./32) bf16 probs + partial row sums
  gemm_sc8<<<dim3(544), 256, 0, stream>>>(q8, k8, probs, part);

  // 5. inv row sums
  reduce_invl<<<dim3(MF / 256), 256, 0, stream>>>(part, invl);

  // 6. out = (P vw) * invl + bo   (final, fp32, causal k-limit, CU-balanced)
  gemm_pv_out<<<dim3(512), 256, 0, stream>>>(probs, vwT_b, out, invl, bo);
}